// Round 1
// baseline (579.238 us; speedup 1.0000x reference)
//
#include <hip/hip_runtime.h>

// ---------------------------------------------------------------------------
// CrossAttention (trinity mask) on MI355X.
// B=4, N=2048 (IMG=1536 in 3 chunks of 512, TXT=512), C=1024, H=16, d=64.
// Pipeline: cvt(q,kv)->fp16 ; W^T fp16 ; GEMM Qproj/Kproj (heads layout),
//           Vproj (transposed heads layout) ; flash attention (block-sparse) ;
//           GEMM out-proj (+bias, f32 out).
// fp16 fragments + f32 accumulation everywhere (bf16 would blow the absmax
// threshold through the 4-matmul chain; fp16 is same MFMA rate on gfx950).
// ---------------------------------------------------------------------------

typedef _Float16 h16;
typedef _Float16 f16x8 __attribute__((ext_vector_type(8)));
typedef float f32x4 __attribute__((ext_vector_type(4)));
typedef unsigned short u16;

#define BATCH 4
#define NTOK  2048
#define CDIM  1024
#define NHEAD 16
#define HDIM  64
#define IMGTOK 1536
#define MROWS (BATCH * NTOK)   // 8192

__device__ __forceinline__ void gload_lds16(const void* g, void* l) {
  __builtin_amdgcn_global_load_lds(
      (const __attribute__((address_space(1))) unsigned int*)g,
      (__attribute__((address_space(3))) unsigned int*)l, 16, 0, 0);
}

// ---------------------------------------------------------------------------
// f32 -> fp16 elementwise convert, 8 elems/thread
__global__ __launch_bounds__(256)
void cvt_f16(const float* __restrict__ s, h16* __restrict__ d) {
  size_t i = ((size_t)blockIdx.x * 256 + threadIdx.x) * 8;
  float4 a = *(const float4*)(s + i);
  float4 b = *(const float4*)(s + i + 4);
  f16x8 o;
  o[0] = (h16)a.x; o[1] = (h16)a.y; o[2] = (h16)a.z; o[3] = (h16)a.w;
  o[4] = (h16)b.x; o[5] = (h16)b.y; o[6] = (h16)b.z; o[7] = (h16)b.w;
  *(f16x8*)(d + i) = o;
}

// ---------------------------------------------------------------------------
// W [K=1024][N=1024] f32  ->  WT [N][K] fp16   (4 weights via blockIdx.z)
__global__ __launch_bounds__(256)
void wtrans(const float* __restrict__ W0, const float* __restrict__ W1,
            const float* __restrict__ W2, const float* __restrict__ W3,
            h16* __restrict__ T0, h16* __restrict__ T1,
            h16* __restrict__ T2, h16* __restrict__ T3) {
  const float* W; h16* T;
  switch (blockIdx.z) {
    case 0: W = W0; T = T0; break;
    case 1: W = W1; T = T1; break;
    case 2: W = W2; T = T2; break;
    default: W = W3; T = T3; break;
  }
  __shared__ float t[32][33];
  const int n0 = blockIdx.x * 32, k0 = blockIdx.y * 32;
  const int tx = threadIdx.x, ty = threadIdx.y;  // (32,8)
#pragma unroll
  for (int i = 0; i < 4; i++)
    t[ty + 8 * i][tx] = W[(size_t)(k0 + ty + 8 * i) * CDIM + n0 + tx];
  __syncthreads();
#pragma unroll
  for (int i = 0; i < 4; i++)
    T[(size_t)(n0 + ty + 8 * i) * CDIM + k0 + tx] = (h16)t[tx][ty + 8 * i];
}

// ---------------------------------------------------------------------------
// GEMM: C[M=8192][1024] = X[8192][1024] @ WT^T + bias
// WT is [N][K] (row-major, K contiguous). 128x128 tile, BK=32, 4 waves.
// MODE 0: f32 out row-major (+bias)
// MODE 1: fp16 out heads layout   [B,H,N,64]
// MODE 2: fp16 out heads-T layout [B,H,64,N]
template <int MODE>
__global__ __launch_bounds__(256)
void gemm_bt(const h16* __restrict__ X, const h16* __restrict__ WT,
             const float* __restrict__ bias, void* __restrict__ outp) {
  __shared__ __attribute__((aligned(16))) h16 As[128 * 32];
  __shared__ __attribute__((aligned(16))) h16 Bs[128 * 32];
  const int tid = threadIdx.x;
  const int lane = tid & 63;
  const int w = tid >> 6;
  const int wr = w >> 1, wc = w & 1;
  const int l15 = lane & 15, lhi = lane >> 4;
  const int m0 = blockIdx.y * 128;
  const int n0 = blockIdx.x * 128;

  f32x4 acc[4][4] = {};

  // staging: 512 chunks of 16B per tile per matrix; 2 chunks/thread/matrix
  const int sr = tid >> 2;            // row (first half)
  const int sc = (tid & 3) * 8;       // h16 col offset
  const h16* gA0 = X + (size_t)(m0 + sr) * CDIM + sc;
  const h16* gA1 = gA0 + (size_t)64 * CDIM;
  const h16* gB0 = WT + (size_t)(n0 + sr) * CDIM + sc;
  const h16* gB1 = gB0 + (size_t)64 * CDIM;
  h16* lA0 = As + tid * 8;
  h16* lA1 = As + (256 + tid) * 8;
  h16* lB0 = Bs + tid * 8;
  h16* lB1 = Bs + (256 + tid) * 8;

  for (int kt = 0; kt < CDIM / 32; ++kt) {
    gload_lds16(gA0 + kt * 32, lA0);
    gload_lds16(gA1 + kt * 32, lA1);
    gload_lds16(gB0 + kt * 32, lB0);
    gload_lds16(gB1 + kt * 32, lB1);
    __syncthreads();   // compiler drains vmcnt before barrier
    f16x8 a[4], bb[4];
#pragma unroll
    for (int i = 0; i < 4; i++)
      a[i] = *(const f16x8*)(As + (wr * 64 + i * 16 + l15) * 32 + lhi * 8);
#pragma unroll
    for (int i = 0; i < 4; i++)
      bb[i] = *(const f16x8*)(Bs + (wc * 64 + i * 16 + l15) * 32 + lhi * 8);
#pragma unroll
    for (int i = 0; i < 4; i++)
#pragma unroll
      for (int j = 0; j < 4; j++)
        acc[i][j] = __builtin_amdgcn_mfma_f32_16x16x32_f16(a[i], bb[j], acc[i][j], 0, 0, 0);
    __syncthreads();
  }

  // epilogue: D layout col=lane&15, row=(lane>>4)*4+reg
#pragma unroll
  for (int j = 0; j < 4; j++) {
    const int gc = n0 + wc * 64 + j * 16 + l15;
    const float bval = bias[gc];
#pragma unroll
    for (int i = 0; i < 4; i++) {
      const int grb = m0 + wr * 64 + i * 16 + lhi * 4;
#pragma unroll
      for (int r = 0; r < 4; r++) {
        const float v = acc[i][j][r] + bval;
        const int gr = grb + r;
        if constexpr (MODE == 0) {
          ((float*)outp)[(size_t)gr * CDIM + gc] = v;
        } else {
          const int bidx = gr >> 11, n = gr & (NTOK - 1);
          const int hh = gc >> 6, dd = gc & 63;
          if constexpr (MODE == 1)
            ((h16*)outp)[(((size_t)(bidx * NHEAD + hh)) * NTOK + n) * HDIM + dd] = (h16)v;
          else
            ((h16*)outp)[(((size_t)(bidx * NHEAD + hh)) * HDIM + dd) * NTOK + n] = (h16)v;
        }
      }
    }
  }
}

// ---------------------------------------------------------------------------
// Flash attention with trinity mask.
// Grid (32 qblocks, 64 bh). Block: 4 waves, each owns 16 q-rows.
// Image q-block: keys = own 512-chunk only (no masking needed).
// Text  q-block: keys = [0, q0+64); causal mask only on text-region tiles.
__global__ __launch_bounds__(256)
void attn_kernel(const h16* __restrict__ Qh, const h16* __restrict__ Kh,
                 const h16* __restrict__ VTh, h16* __restrict__ AX) {
  __shared__ __attribute__((aligned(16))) h16 Klds[32 * 72];    // row stride 72 (pad 8)
  __shared__ __attribute__((aligned(16))) h16 Vlds[64 * 40];    // VT rows, stride 40 (pad 8)
  __shared__ __attribute__((aligned(16))) h16 Plds[4][16 * 40]; // per-wave P scratch

  const int tid = threadIdx.x;
  const int lane = tid & 63;
  const int w = tid >> 6;
  const int l15 = lane & 15, lhi = lane >> 4;
  const int bh = blockIdx.y;
  const int qblk = blockIdx.x;
  const int b = bh >> 4, h = bh & 15;
  const int q0 = qblk * 64;

  const h16* qbase = Qh + (size_t)bh * NTOK * HDIM;
  const h16* kbase = Kh + (size_t)bh * NTOK * HDIM;
  const h16* vbase = VTh + (size_t)bh * HDIM * NTOK;

  // Q fragments (A operand): row = lane&15, k = (lane>>4)*8..+8
  const int qrow = q0 + w * 16 + l15;
  f16x8 qf0 = *(const f16x8*)(qbase + (size_t)qrow * HDIM + lhi * 8);
  f16x8 qf1 = *(const f16x8*)(qbase + (size_t)qrow * HDIM + 32 + lhi * 8);

  const bool is_img = (q0 < IMGTOK);
  int kstart, kend;
  if (is_img) { kstart = q0 & ~511; kend = kstart + 512; }
  else        { kstart = 0;         kend = q0 + 64; }

  float m_r[4], l_r[4];
  f32x4 o[4] = {};
#pragma unroll
  for (int r = 0; r < 4; r++) { m_r[r] = -3.0e38f; l_r[r] = 0.f; }

  const int skr = tid >> 3, skc = (tid & 7) * 8;  // K stage: 32 rows x 8 chunks
  const int svr = tid >> 2, svc = (tid & 3) * 8;  // V stage: 64 rows x 4 chunks
  h16* pl = &Plds[w][0];
  const float sc = 0.125f * 1.44269504088896f;    // scale * log2(e)

  for (int k0 = kstart; k0 < kend; k0 += 32) {
    *(uint4*)(Klds + skr * 72 + skc) =
        *(const uint4*)(kbase + (size_t)(k0 + skr) * HDIM + skc);
    *(uint4*)(Vlds + svr * 40 + svc) =
        *(const uint4*)(vbase + (size_t)svr * NTOK + k0 + svc);
    __syncthreads();

    // S = Q K^T (two 16-key halves), f32
    f32x4 s[2];
#pragma unroll
    for (int hk = 0; hk < 2; ++hk) {
      f16x8 kf0 = *(const f16x8*)(Klds + (hk * 16 + l15) * 72 + lhi * 8);
      f16x8 kf1 = *(const f16x8*)(Klds + (hk * 16 + l15) * 72 + 32 + lhi * 8);
      f32x4 acc = {};
      acc = __builtin_amdgcn_mfma_f32_16x16x32_f16(qf0, kf0, acc, 0, 0, 0);
      acc = __builtin_amdgcn_mfma_f32_16x16x32_f16(qf1, kf1, acc, 0, 0, 0);
      s[hk] = acc;
    }

    const bool need_mask = (!is_img) && (k0 + 31 >= IMGTOK);
#pragma unroll
    for (int r = 0; r < 4; r++) {
      float s0 = s[0][r] * sc;
      float s1 = s[1][r] * sc;
      if (need_mask) {
        const int qg = q0 + w * 16 + lhi * 4 + r;
        const int kg0 = k0 + l15, kg1 = k0 + 16 + l15;
        if (kg0 >= IMGTOK && kg0 > qg) s0 = -1e30f;
        if (kg1 >= IMGTOK && kg1 > qg) s1 = -1e30f;
      }
      float vmax = fmaxf(s0, s1);
      vmax = fmaxf(vmax, __shfl_xor(vmax, 1));
      vmax = fmaxf(vmax, __shfl_xor(vmax, 2));
      vmax = fmaxf(vmax, __shfl_xor(vmax, 4));
      vmax = fmaxf(vmax, __shfl_xor(vmax, 8));
      const float mnew = fmaxf(m_r[r], vmax);
      const float corr = exp2f(m_r[r] - mnew);
      m_r[r] = mnew;
      const float p0 = exp2f(s0 - mnew);
      const float p1 = exp2f(s1 - mnew);
      float rs = p0 + p1;
      rs += __shfl_xor(rs, 1);
      rs += __shfl_xor(rs, 2);
      rs += __shfl_xor(rs, 4);
      rs += __shfl_xor(rs, 8);
      l_r[r] = l_r[r] * corr + rs;
#pragma unroll
      for (int dt = 0; dt < 4; dt++) o[dt][r] *= corr;
      // P scratch: row = q-local, col = key-local
      pl[(lhi * 4 + r) * 40 + l15] = (h16)p0;
      pl[(lhi * 4 + r) * 40 + 16 + l15] = (h16)p1;
    }
    // wave-private LDS write->read: order + completion, no block barrier needed
    asm volatile("s_waitcnt lgkmcnt(0)" ::: "memory");

    // PV: A = P[16q x 32k], B = V[32k x 16d] (from VT rows)
    f16x8 pf = *(const f16x8*)(pl + l15 * 40 + lhi * 8);
#pragma unroll
    for (int dt = 0; dt < 4; dt++) {
      f16x8 vf = *(const f16x8*)(Vlds + (dt * 16 + l15) * 40 + lhi * 8);
      o[dt] = __builtin_amdgcn_mfma_f32_16x16x32_f16(pf, vf, o[dt], 0, 0, 0);
    }
    __syncthreads();  // protect K/V LDS before next stage
  }

  // epilogue: AX[b*2048+q][h*64 + dt*16 + col]
  const int qg0 = q0 + w * 16 + lhi * 4;
#pragma unroll
  for (int r = 0; r < 4; r++) {
    const float inv = 1.0f / l_r[r];
    const size_t row = (size_t)(b * NTOK + qg0 + r);
#pragma unroll
    for (int dt = 0; dt < 4; dt++) {
      const int col = h * 64 + dt * 16 + l15;
      AX[row * CDIM + col] = (h16)(o[dt][r] * inv);
    }
  }
}

// ---------------------------------------------------------------------------
extern "C" void kernel_launch(void* const* d_in, const int* in_sizes, int n_in,
                              void* d_out, int out_size, void* d_ws, size_t ws_size,
                              hipStream_t stream) {
  (void)in_sizes; (void)n_in; (void)out_size; (void)ws_size;
  const float* q  = (const float*)d_in[0];
  const float* kv = (const float*)d_in[1];
  const float* Wq = (const float*)d_in[2];
  const float* bq = (const float*)d_in[3];
  const float* Wk = (const float*)d_in[4];
  const float* bk = (const float*)d_in[5];
  const float* Wv = (const float*)d_in[6];
  const float* bv = (const float*)d_in[7];
  const float* Wo = (const float*)d_in[8];
  const float* bo = (const float*)d_in[9];
  float* out = (float*)d_out;

  char* ws = (char*)d_ws;
  const size_t SZ_MK = (size_t)MROWS * CDIM * sizeof(h16);  // 16 MB
  const size_t SZ_W  = (size_t)CDIM * CDIM * sizeof(h16);   // 2 MB
  h16* qb  = (h16*)(ws);
  h16* kvb = (h16*)(ws + SZ_MK);
  h16* wqt = (h16*)(ws + 2 * SZ_MK);
  h16* wkt = (h16*)(ws + 2 * SZ_MK + SZ_W);
  h16* wvt = (h16*)(ws + 2 * SZ_MK + 2 * SZ_W);
  h16* wot = (h16*)(ws + 2 * SZ_MK + 3 * SZ_W);
  h16* Qh  = (h16*)(ws + 2 * SZ_MK + 4 * SZ_W);
  h16* Kh  = (h16*)(ws + 3 * SZ_MK + 4 * SZ_W);
  h16* VTh = (h16*)(ws + 4 * SZ_MK + 4 * SZ_W);
  h16* ax  = (h16*)(ws);  // overlays qb (qb dead after Q projection)

  cvt_f16<<<4096, 256, 0, stream>>>(q, qb);
  cvt_f16<<<4096, 256, 0, stream>>>(kv, kvb);
  wtrans<<<dim3(32, 32, 4), dim3(32, 8), 0, stream>>>(Wq, Wk, Wv, Wo,
                                                      wqt, wkt, wvt, wot);
  gemm_bt<1><<<dim3(8, 64), 256, 0, stream>>>(qb, wqt, bq, (void*)Qh);
  gemm_bt<1><<<dim3(8, 64), 256, 0, stream>>>(kvb, wkt, bk, (void*)Kh);
  gemm_bt<2><<<dim3(8, 64), 256, 0, stream>>>(kvb, wvt, bv, (void*)VTh);
  attn_kernel<<<dim3(32, 64), 256, 0, stream>>>(Qh, Kh, VTh, ax);
  gemm_bt<0><<<dim3(8, 64), 256, 0, stream>>>(ax, wot, bo, (void*)out);
}

// Round 2
// 406.836 us; speedup vs baseline: 1.4238x; 1.4238x over previous
//
#include <hip/hip_runtime.h>

// ---------------------------------------------------------------------------
// CrossAttention (trinity mask) on MI355X.
// B=4, N=2048 (IMG=1536 in 3 chunks of 512, TXT=512), C=1024, H=16, d=64.
// R2: attention rewritten as 2-phase double-buffered pipeline (KVBLK=64,
//     global_load_lds + XOR-swizzled LDS, raw s_barrier, XCD-grouped bh),
//     GEMMs get the same stage-before-compute prefetch.
// fp16 fragments + f32 accumulation (bf16 would blow absmax through the
// 4-matmul chain; fp16 is same MFMA rate on gfx950).
// ---------------------------------------------------------------------------

typedef _Float16 h16;
typedef _Float16 f16x8 __attribute__((ext_vector_type(8)));
typedef float f32x4 __attribute__((ext_vector_type(4)));

#define BATCH 4
#define NTOK  2048
#define CDIM  1024
#define NHEAD 16
#define HDIM  64
#define IMGTOK 1536
#define MROWS (BATCH * NTOK)   // 8192

__device__ __forceinline__ void gload_lds16(const void* g, void* l) {
  __builtin_amdgcn_global_load_lds(
      (const __attribute__((address_space(1))) unsigned int*)g,
      (__attribute__((address_space(3))) unsigned int*)l, 16, 0, 0);
}
__device__ __forceinline__ void wait_vm0() {
  asm volatile("s_waitcnt vmcnt(0)" ::: "memory");
}

// ---------------------------------------------------------------------------
// f32 -> fp16 elementwise convert, 8 elems/thread
__global__ __launch_bounds__(256)
void cvt_f16(const float* __restrict__ s, h16* __restrict__ d) {
  size_t i = ((size_t)blockIdx.x * 256 + threadIdx.x) * 8;
  float4 a = *(const float4*)(s + i);
  float4 b = *(const float4*)(s + i + 4);
  f16x8 o;
  o[0] = (h16)a.x; o[1] = (h16)a.y; o[2] = (h16)a.z; o[3] = (h16)a.w;
  o[4] = (h16)b.x; o[5] = (h16)b.y; o[6] = (h16)b.z; o[7] = (h16)b.w;
  *(f16x8*)(d + i) = o;
}

// ---------------------------------------------------------------------------
// W [K=1024][N=1024] f32  ->  WT [N][K] fp16   (4 weights via blockIdx.z)
__global__ __launch_bounds__(256)
void wtrans(const float* __restrict__ W0, const float* __restrict__ W1,
            const float* __restrict__ W2, const float* __restrict__ W3,
            h16* __restrict__ T0, h16* __restrict__ T1,
            h16* __restrict__ T2, h16* __restrict__ T3) {
  const float* W; h16* T;
  switch (blockIdx.z) {
    case 0: W = W0; T = T0; break;
    case 1: W = W1; T = T1; break;
    case 2: W = W2; T = T2; break;
    default: W = W3; T = T3; break;
  }
  __shared__ float t[32][33];
  const int n0 = blockIdx.x * 32, k0 = blockIdx.y * 32;
  const int tx = threadIdx.x, ty = threadIdx.y;  // (32,8)
#pragma unroll
  for (int i = 0; i < 4; i++)
    t[ty + 8 * i][tx] = W[(size_t)(k0 + ty + 8 * i) * CDIM + n0 + tx];
  __syncthreads();
#pragma unroll
  for (int i = 0; i < 4; i++)
    T[(size_t)(n0 + ty + 8 * i) * CDIM + k0 + tx] = (h16)t[tx][ty + 8 * i];
}

// ---------------------------------------------------------------------------
// GEMM: C[M=8192][1024] = X[8192][1024] @ WT^T + bias
// WT is [N][K] row-major. 128x128 tile, BK=32, 4 waves, 2-phase prefetch
// (double-buffered LDS, stage-before-compute, one raw barrier per K-step).
// MODE 0: f32 out row-major (+bias)
// MODE 1: fp16 out heads layout   [B,H,N,64]
// MODE 2: fp16 out heads-T layout [B,H,64,N]
template <int MODE>
__global__ __launch_bounds__(256)
void gemm_bt(const h16* __restrict__ X, const h16* __restrict__ WT,
             const float* __restrict__ bias, void* __restrict__ outp) {
  __shared__ __attribute__((aligned(16))) h16 As[2][128 * 32];
  __shared__ __attribute__((aligned(16))) h16 Bs[2][128 * 32];
  const int tid = threadIdx.x;
  const int lane = tid & 63;
  const int w = tid >> 6;
  const int wr = w >> 1, wc = w & 1;
  const int l15 = lane & 15, lhi = lane >> 4;
  const int m0 = blockIdx.y * 128;
  const int n0 = blockIdx.x * 128;

  f32x4 acc[4][4] = {};

  const int sr = tid >> 2;            // staging row (first half)
  const int sc = (tid & 3) * 8;       // h16 col offset
  const h16* gA0 = X + (size_t)(m0 + sr) * CDIM + sc;
  const h16* gA1 = gA0 + (size_t)64 * CDIM;
  const h16* gB0 = WT + (size_t)(n0 + sr) * CDIM + sc;
  const h16* gB1 = gB0 + (size_t)64 * CDIM;

#define GSTAGE(bufi, kt)                                        \
  do {                                                          \
    gload_lds16(gA0 + (kt) * 32, As[bufi] + tid * 8);           \
    gload_lds16(gA1 + (kt) * 32, As[bufi] + (256 + tid) * 8);   \
    gload_lds16(gB0 + (kt) * 32, Bs[bufi] + tid * 8);           \
    gload_lds16(gB1 + (kt) * 32, Bs[bufi] + (256 + tid) * 8);   \
  } while (0)

  GSTAGE(0, 0);
  wait_vm0();
  __builtin_amdgcn_s_barrier();
  int cur = 0;
  for (int kt = 0; kt < CDIM / 32; ++kt) {
    if (kt + 1 < CDIM / 32) GSTAGE(cur ^ 1, kt + 1);
    const h16* Ac = As[cur];
    const h16* Bc = Bs[cur];
    f16x8 a[4], bb[4];
#pragma unroll
    for (int i = 0; i < 4; i++)
      a[i] = *(const f16x8*)(Ac + (wr * 64 + i * 16 + l15) * 32 + lhi * 8);
#pragma unroll
    for (int i = 0; i < 4; i++)
      bb[i] = *(const f16x8*)(Bc + (wc * 64 + i * 16 + l15) * 32 + lhi * 8);
    __builtin_amdgcn_s_setprio(1);
#pragma unroll
    for (int i = 0; i < 4; i++)
#pragma unroll
      for (int j = 0; j < 4; j++)
        acc[i][j] = __builtin_amdgcn_mfma_f32_16x16x32_f16(a[i], bb[j], acc[i][j], 0, 0, 0);
    __builtin_amdgcn_s_setprio(0);
    wait_vm0();
    __builtin_amdgcn_s_barrier();
    cur ^= 1;
  }
#undef GSTAGE

  // epilogue: D layout col=lane&15, row=(lane>>4)*4+reg
#pragma unroll
  for (int j = 0; j < 4; j++) {
    const int gc = n0 + wc * 64 + j * 16 + l15;
    const float bval = bias[gc];
#pragma unroll
    for (int i = 0; i < 4; i++) {
      const int grb = m0 + wr * 64 + i * 16 + lhi * 4;
#pragma unroll
      for (int r = 0; r < 4; r++) {
        const float v = acc[i][j][r] + bval;
        const int gr = grb + r;
        if constexpr (MODE == 0) {
          ((float*)outp)[(size_t)gr * CDIM + gc] = v;
        } else {
          const int bidx = gr >> 11, n = gr & (NTOK - 1);
          const int hh = gc >> 6, dd = gc & 63;
          if constexpr (MODE == 1)
            ((h16*)outp)[(((size_t)(bidx * NHEAD + hh)) * NTOK + n) * HDIM + dd] = (h16)v;
          else
            ((h16*)outp)[(((size_t)(bidx * NHEAD + hh)) * HDIM + dd) * NTOK + n] = (h16)v;
        }
      }
    }
  }
}

// ---------------------------------------------------------------------------
// Flash attention with trinity mask. 2-phase pipeline, KVBLK=64.
// Grid: 2048 1D blocks. id&7 -> XCD slot (round-robin dispatch), each XCD
// owns 8 bh's (K+V = 4 MB = one L2); text-heavy qblks dispatched first.
// LDS: K/V double-buffered, XOR-swizzled (linear DMA dest + inverse-swizzled
// global source + swizzled ds_read). Total = 40960 B -> 4 blocks/CU.
__global__ __launch_bounds__(256)
void attn_kernel(const h16* __restrict__ Qh, const h16* __restrict__ Kh,
                 const h16* __restrict__ VTh, h16* __restrict__ AX) {
  __shared__ __attribute__((aligned(16))) h16 Kb[2][64 * 64];
  __shared__ __attribute__((aligned(16))) h16 Vb[2][64 * 64];
  __shared__ __attribute__((aligned(16))) h16 Pl[4][16 * 64];  // XOR-swizzled

  const int tid = threadIdx.x;
  const int lane = tid & 63;
  const int w = tid >> 6;
  const int l15 = lane & 15, lhi = lane >> 4;

  const int id = blockIdx.x;
  const int pos = id >> 3;
  const int bh = (id & 7) * 8 + (pos >> 5);   // XCD-grouped bh
  const int qblk = 31 - (pos & 31);           // text-first (long blocks early)
  const int b = bh >> 4, h = bh & 15;
  const int q0 = qblk * 64;

  const h16* qbase = Qh + (size_t)bh * NTOK * HDIM;
  const h16* kbase = Kh + (size_t)bh * NTOK * HDIM;
  const h16* vbase = VTh + (size_t)bh * HDIM * NTOK;

  // Q fragments (A operand): row = lane&15, k = (lane>>4)*8..+8
  const int qrow = q0 + w * 16 + l15;
  const f16x8 qf0 = *(const f16x8*)(qbase + (size_t)qrow * HDIM + lhi * 8);
  const f16x8 qf1 = *(const f16x8*)(qbase + (size_t)qrow * HDIM + 32 + lhi * 8);

  const bool is_img = (q0 < IMGTOK);
  int kstart, kend;
  if (is_img) { kstart = q0 & ~511; kend = kstart + 512; }
  else        { kstart = 0;         kend = q0 + 64; }
  const int nt = (kend - kstart) >> 6;

  float m_r[4], l_r[4];
  f32x4 o[4] = {};
#pragma unroll
  for (int r = 0; r < 4; r++) { m_r[r] = -3.0e38f; l_r[r] = 0.f; }

  // staging: 512 16B-chunks per matrix = 2 rounds x 256 threads.
  // physical chunk p -> row p>>3; logical col-chunk = (p&7) ^ (row&7).
  const int srow = tid >> 3;
  const int scc = (tid & 7) ^ (srow & 7);
#define ASTAGE(bufi, k0s)                                                     \
  do {                                                                        \
    gload_lds16(kbase + (size_t)((k0s) + srow) * HDIM + scc * 8,              \
                Kb[bufi] + tid * 8);                                          \
    gload_lds16(kbase + (size_t)((k0s) + 32 + srow) * HDIM + scc * 8,         \
                Kb[bufi] + (256 + tid) * 8);                                  \
    gload_lds16(vbase + (size_t)srow * NTOK + (k0s) + scc * 8,                \
                Vb[bufi] + tid * 8);                                          \
    gload_lds16(vbase + (size_t)(32 + srow) * NTOK + (k0s) + scc * 8,         \
                Vb[bufi] + (256 + tid) * 8);                                  \
  } while (0)

  h16* pl = &Pl[w][0];
  const float sc = 0.125f * 1.44269504088896f;  // scale * log2(e)
  const int x0 = (lhi ^ (l15 & 7)) * 8;          // swizzled chunk offsets
  const int x1 = ((lhi + 4) ^ (l15 & 7)) * 8;

  ASTAGE(0, kstart);
  wait_vm0();
  __builtin_amdgcn_s_barrier();
  int cur = 0;

  for (int t = 0; t < nt; ++t) {
    const int k0 = kstart + t * 64;
    if (t + 1 < nt) ASTAGE(cur ^ 1, kstart + (t + 1) * 64);

    // ---- S = Q K^T : 4 halves of 16 keys, f32 -------------------------
    const h16* Kc = Kb[cur];
    f32x4 s[4];
    __builtin_amdgcn_s_setprio(1);
#pragma unroll
    for (int hk = 0; hk < 4; ++hk) {
      const h16* kr = Kc + (hk * 16 + l15) * 64;
      const f16x8 kfa = *(const f16x8*)(kr + x0);
      const f16x8 kfb = *(const f16x8*)(kr + x1);
      f32x4 acc = {};
      acc = __builtin_amdgcn_mfma_f32_16x16x32_f16(qf0, kfa, acc, 0, 0, 0);
      acc = __builtin_amdgcn_mfma_f32_16x16x32_f16(qf1, kfb, acc, 0, 0, 0);
      s[hk] = acc;
    }
    __builtin_amdgcn_s_setprio(0);

    // ---- online softmax ----------------------------------------------
    const bool need_mask = (!is_img) && (k0 + 63 >= IMGTOK);
#pragma unroll
    for (int r = 0; r < 4; ++r) {
      float sv[4];
#pragma unroll
      for (int hk = 0; hk < 4; ++hk) sv[hk] = s[hk][r] * sc;
      if (need_mask) {
        const int qg = q0 + w * 16 + lhi * 4 + r;
#pragma unroll
        for (int hk = 0; hk < 4; ++hk) {
          const int kg = k0 + hk * 16 + l15;
          if (kg >= IMGTOK && kg > qg) sv[hk] = -1e30f;
        }
      }
      float vmax = fmaxf(fmaxf(sv[0], sv[1]), fmaxf(sv[2], sv[3]));
      vmax = fmaxf(vmax, __shfl_xor(vmax, 1));
      vmax = fmaxf(vmax, __shfl_xor(vmax, 2));
      vmax = fmaxf(vmax, __shfl_xor(vmax, 4));
      vmax = fmaxf(vmax, __shfl_xor(vmax, 8));
      const float mnew = fmaxf(m_r[r], vmax);
      const float corr = exp2f(m_r[r] - mnew);
      m_r[r] = mnew;
      float p[4];
      float rs = 0.f;
#pragma unroll
      for (int hk = 0; hk < 4; ++hk) { p[hk] = exp2f(sv[hk] - mnew); rs += p[hk]; }
      rs += __shfl_xor(rs, 1);
      rs += __shfl_xor(rs, 2);
      rs += __shfl_xor(rs, 4);
      rs += __shfl_xor(rs, 8);
      l_r[r] = l_r[r] * corr + rs;
#pragma unroll
      for (int dt = 0; dt < 4; dt++) o[dt][r] *= corr;
      // P scratch (XOR-swizzled [16][64]): row=q-local, col=key-local
      const int prow = lhi * 4 + r;
      h16* pr = pl + prow * 64;
#pragma unroll
      for (int hk = 0; hk < 4; ++hk) {
        const int c = hk * 16 + l15;
        pr[((c >> 3) ^ (prow & 7)) * 8 + (c & 7)] = (h16)p[hk];
      }
    }
    // wave-private LDS write->read ordering
    asm volatile("s_waitcnt lgkmcnt(0)" ::: "memory");
    __builtin_amdgcn_sched_barrier(0);

    // ---- PV: A = P[16q x 64k], B = V[64k x 16d] ----------------------
    const h16* Vc = Vb[cur];
    const f16x8 pf0 = *(const f16x8*)(pl + l15 * 64 + x0);
    const f16x8 pf1 = *(const f16x8*)(pl + l15 * 64 + x1);
    __builtin_amdgcn_s_setprio(1);
#pragma unroll
    for (int dt = 0; dt < 4; dt++) {
      const h16* vr = Vc + (dt * 16 + l15) * 64;
      const f16x8 vfa = *(const f16x8*)(vr + x0);
      const f16x8 vfb = *(const f16x8*)(vr + x1);
      o[dt] = __builtin_amdgcn_mfma_f32_16x16x32_f16(pf0, vfa, o[dt], 0, 0, 0);
      o[dt] = __builtin_amdgcn_mfma_f32_16x16x32_f16(pf1, vfb, o[dt], 0, 0, 0);
    }
    __builtin_amdgcn_s_setprio(0);

    wait_vm0();                       // next tile's DMA landed
    __builtin_amdgcn_s_barrier();     // all waves done with buf[cur]
    cur ^= 1;
  }
#undef ASTAGE

  // epilogue: AX[b*2048+q][h*64 + dt*16 + col]
  const int qg0 = q0 + w * 16 + lhi * 4;
#pragma unroll
  for (int r = 0; r < 4; r++) {
    const float inv = 1.0f / l_r[r];
    const size_t row = (size_t)(b * NTOK + qg0 + r);
#pragma unroll
    for (int dt = 0; dt < 4; dt++) {
      const int col = h * 64 + dt * 16 + l15;
      AX[row * CDIM + col] = (h16)(o[dt][r] * inv);
    }
  }
}

// ---------------------------------------------------------------------------
extern "C" void kernel_launch(void* const* d_in, const int* in_sizes, int n_in,
                              void* d_out, int out_size, void* d_ws, size_t ws_size,
                              hipStream_t stream) {
  (void)in_sizes; (void)n_in; (void)out_size; (void)ws_size;
  const float* q  = (const float*)d_in[0];
  const float* kv = (const float*)d_in[1];
  const float* Wq = (const float*)d_in[2];
  const float* bq = (const float*)d_in[3];
  const float* Wk = (const float*)d_in[4];
  const float* bk = (const float*)d_in[5];
  const float* Wv = (const float*)d_in[6];
  const float* bv = (const float*)d_in[7];
  const float* Wo = (const float*)d_in[8];
  const float* bo = (const float*)d_in[9];
  float* out = (float*)d_out;

  char* ws = (char*)d_ws;
  const size_t SZ_MK = (size_t)MROWS * CDIM * sizeof(h16);  // 16 MB
  const size_t SZ_W  = (size_t)CDIM * CDIM * sizeof(h16);   // 2 MB
  h16* qb  = (h16*)(ws);
  h16* kvb = (h16*)(ws + SZ_MK);
  h16* wqt = (h16*)(ws + 2 * SZ_MK);
  h16* wkt = (h16*)(ws + 2 * SZ_MK + SZ_W);
  h16* wvt = (h16*)(ws + 2 * SZ_MK + 2 * SZ_W);
  h16* wot = (h16*)(ws + 2 * SZ_MK + 3 * SZ_W);
  h16* Qh  = (h16*)(ws + 2 * SZ_MK + 4 * SZ_W);
  h16* Kh  = (h16*)(ws + 3 * SZ_MK + 4 * SZ_W);
  h16* VTh = (h16*)(ws + 4 * SZ_MK + 4 * SZ_W);
  h16* ax  = (h16*)(ws);  // overlays qb (qb dead after Q projection)

  cvt_f16<<<4096, 256, 0, stream>>>(q, qb);
  cvt_f16<<<4096, 256, 0, stream>>>(kv, kvb);
  wtrans<<<dim3(32, 32, 4), dim3(32, 8), 0, stream>>>(Wq, Wk, Wv, Wo,
                                                      wqt, wkt, wvt, wot);
  gemm_bt<1><<<dim3(8, 64), 256, 0, stream>>>(qb, wqt, bq, (void*)Qh);
  gemm_bt<1><<<dim3(8, 64), 256, 0, stream>>>(kvb, wkt, bk, (void*)Kh);
  gemm_bt<2><<<dim3(8, 64), 256, 0, stream>>>(kvb, wvt, bv, (void*)VTh);
  attn_kernel<<<2048, 256, 0, stream>>>(Qh, Kh, VTh, ax);
  gemm_bt<0><<<dim3(8, 64), 256, 0, stream>>>(ax, wot, bo, (void*)out);
}

// Round 3
// 339.560 us; speedup vs baseline: 1.7058x; 1.1981x over previous
//
#include <hip/hip_runtime.h>

// ---------------------------------------------------------------------------
// CrossAttention (trinity mask) on MI355X.
// B=4, N=2048 (IMG=1536 in 3 chunks of 512, TXT=512), C=1024, H=16, d=64.
// R3: attn gets defer-max + deferred row-sum (kills per-tile shfl chains);
//     GEMM gets 4-buffer counted-vmcnt pipeline + XOR-swizzled LDS +
//     LDS-transpose epilogue for the V^T output (kills write amplification).
// fp16 fragments + f32 accumulation (bf16 would blow absmax through the
// 4-matmul chain; fp16 is same MFMA rate on gfx950).
// ---------------------------------------------------------------------------

typedef _Float16 h16;
typedef _Float16 f16x8 __attribute__((ext_vector_type(8)));
typedef float f32x4 __attribute__((ext_vector_type(4)));

#define BATCH 4
#define NTOK  2048
#define CDIM  1024
#define NHEAD 16
#define HDIM  64
#define IMGTOK 1536
#define MROWS (BATCH * NTOK)   // 8192

__device__ __forceinline__ void gload_lds16(const void* g, void* l) {
  __builtin_amdgcn_global_load_lds(
      (const __attribute__((address_space(1))) unsigned int*)g,
      (__attribute__((address_space(3))) unsigned int*)l, 16, 0, 0);
}

// ---------------------------------------------------------------------------
// f32 -> fp16 elementwise convert, 8 elems/thread
__global__ __launch_bounds__(256)
void cvt_f16(const float* __restrict__ s, h16* __restrict__ d) {
  size_t i = ((size_t)blockIdx.x * 256 + threadIdx.x) * 8;
  float4 a = *(const float4*)(s + i);
  float4 b = *(const float4*)(s + i + 4);
  f16x8 o;
  o[0] = (h16)a.x; o[1] = (h16)a.y; o[2] = (h16)a.z; o[3] = (h16)a.w;
  o[4] = (h16)b.x; o[5] = (h16)b.y; o[6] = (h16)b.z; o[7] = (h16)b.w;
  *(f16x8*)(d + i) = o;
}

// ---------------------------------------------------------------------------
// W [K=1024][N=1024] f32  ->  WT [N][K] fp16   (4 weights via blockIdx.z)
__global__ __launch_bounds__(256)
void wtrans(const float* __restrict__ W0, const float* __restrict__ W1,
            const float* __restrict__ W2, const float* __restrict__ W3,
            h16* __restrict__ T0, h16* __restrict__ T1,
            h16* __restrict__ T2, h16* __restrict__ T3) {
  const float* W; h16* T;
  switch (blockIdx.z) {
    case 0: W = W0; T = T0; break;
    case 1: W = W1; T = T1; break;
    case 2: W = W2; T = T2; break;
    default: W = W3; T = T3; break;
  }
  __shared__ float t[32][33];
  const int n0 = blockIdx.x * 32, k0 = blockIdx.y * 32;
  const int tx = threadIdx.x, ty = threadIdx.y;  // (32,8)
#pragma unroll
  for (int i = 0; i < 4; i++)
    t[ty + 8 * i][tx] = W[(size_t)(k0 + ty + 8 * i) * CDIM + n0 + tx];
  __syncthreads();
#pragma unroll
  for (int i = 0; i < 4; i++)
    T[(size_t)(n0 + ty + 8 * i) * CDIM + k0 + tx] = (h16)t[tx][ty + 8 * i];
}

// ---------------------------------------------------------------------------
// GEMM: C[M=8192][1024] = X[8192][1024] @ WT^T + bias
// WT is [N][K] row-major. 128x128 tile, BK=32, 4 waves.
// 4-buffer pipeline, counted vmcnt (stage t+3; wait vmcnt(8); 1 barrier/iter).
// LDS chunk-XOR swizzle: physical chunk pc at row r holds logical chunk
// pc ^ ((r>>1)&3)  -> frag ds_read_b128 is 2-way (free) instead of 8-way.
// MODE 0: f32 out row-major (+bias)
// MODE 1: fp16 out heads layout   [B,H,N,64]
// MODE 2: fp16 out heads-T layout [B,H,64,N] via LDS-transpose epilogue
template <int MODE>
__global__ __launch_bounds__(256)
void gemm_bt(const h16* __restrict__ X, const h16* __restrict__ WT,
             const float* __restrict__ bias, void* __restrict__ outp) {
  // 4 bufs x (A 4096 + B 4096) h16 = 64 KiB
  __shared__ __attribute__((aligned(16))) h16 smem[4 * 8192];
  const int tid = threadIdx.x;
  const int lane = tid & 63;
  const int w = tid >> 6;
  const int wr = w >> 1, wc = w & 1;
  const int l15 = lane & 15, lhi = lane >> 4;
  const int m0 = blockIdx.y * 128;
  const int n0 = blockIdx.x * 128;

  f32x4 acc[4][4] = {};

  const int sr = tid >> 2;                    // staging row 0..63 (and +64)
  const int pc = tid & 3;                     // physical chunk
  const int lc = pc ^ ((sr >> 1) & 3);        // logical chunk (same for sr+64)
  const h16* gA0 = X + (size_t)(m0 + sr) * CDIM + lc * 8;
  const h16* gA1 = gA0 + (size_t)64 * CDIM;
  const h16* gB0 = WT + (size_t)(n0 + sr) * CDIM + lc * 8;
  const h16* gB1 = gB0 + (size_t)64 * CDIM;

#define GSTAGE(bi, kt)                                      \
  do {                                                      \
    h16* A_ = smem + (bi) * 8192;                           \
    h16* B_ = A_ + 4096;                                    \
    gload_lds16(gA0 + (kt) * 32, A_ + tid * 8);             \
    gload_lds16(gA1 + (kt) * 32, A_ + (256 + tid) * 8);     \
    gload_lds16(gB0 + (kt) * 32, B_ + tid * 8);             \
    gload_lds16(gB1 + (kt) * 32, B_ + (256 + tid) * 8);     \
  } while (0)

  const int NT = CDIM / 32;  // 32
  GSTAGE(0, 0);
  GSTAGE(1, 1);
  GSTAGE(2, 2);
  const int rswz = (l15 >> 1) & 3;   // frag-read chunk swizzle (row-derived)

  for (int kt = 0; kt < NT; ++kt) {
    if (kt + 2 < NT)      asm volatile("s_waitcnt vmcnt(8)" ::: "memory");
    else if (kt + 1 < NT) asm volatile("s_waitcnt vmcnt(4)" ::: "memory");
    else                  asm volatile("s_waitcnt vmcnt(0)" ::: "memory");
    __builtin_amdgcn_s_barrier();
    if (kt + 3 < NT) GSTAGE((kt + 3) & 3, kt + 3);
    const h16* A_ = smem + (kt & 3) * 8192;
    const h16* B_ = A_ + 4096;
    f16x8 a[4], bb[4];
#pragma unroll
    for (int i = 0; i < 4; i++)
      a[i] = *(const f16x8*)(A_ + (wr * 64 + i * 16 + l15) * 32 + (lhi ^ rswz) * 8);
#pragma unroll
    for (int i = 0; i < 4; i++)
      bb[i] = *(const f16x8*)(B_ + (wc * 64 + i * 16 + l15) * 32 + (lhi ^ rswz) * 8);
    __builtin_amdgcn_s_setprio(1);
#pragma unroll
    for (int i = 0; i < 4; i++)
#pragma unroll
      for (int j = 0; j < 4; j++)
        acc[i][j] = __builtin_amdgcn_mfma_f32_16x16x32_f16(a[i], bb[j], acc[i][j], 0, 0, 0);
    __builtin_amdgcn_s_setprio(0);
  }
#undef GSTAGE

  if constexpr (MODE == 2) {
    // LDS-transpose epilogue: T[gcL][grL], chunk-swizzled, then coalesced
    // 256B-row stores into [B,H,64,N].
    __builtin_amdgcn_s_barrier();
    h16* T = smem;  // [128][128] h16, chunk = (grL>>3) ^ (gcL&15)
#pragma unroll
    for (int j = 0; j < 4; j++) {
      const int gcL = wc * 64 + j * 16 + l15;
      const float bval = bias[n0 + gcL];
#pragma unroll
      for (int i = 0; i < 4; i++) {
#pragma unroll
        for (int r = 0; r < 4; r++) {
          const int grL = wr * 64 + i * 16 + lhi * 4 + r;
          const int ch = (grL >> 3) ^ (gcL & 15);
          T[gcL * 128 + ch * 8 + (grL & 7)] = (h16)(acc[i][j][r] + bval);
        }
      }
    }
    __builtin_amdgcn_s_barrier();
    const int bsel = m0 >> 11;
    const int nbase = m0 & (NTOK - 1);
    h16* outh = (h16*)outp;
#pragma unroll
    for (int pass = 0; pass < 8; ++pass) {
      const int rowL = pass * 16 + (tid >> 4);   // 0..127 (output row = gc)
      const int c = tid & 15;                    // chunk of 8 grL
      const int gc = n0 + rowL;
      const int hh = gc >> 6, dd = gc & 63;
      f16x8 v = *(const f16x8*)(T + rowL * 128 + ((c ^ (rowL & 15)) * 8));
      *(f16x8*)(outh + (((size_t)(bsel * NHEAD + hh)) * HDIM + dd) * NTOK +
                nbase + c * 8) = v;
    }
    return;
  }

  // MODE 0/1 epilogue: D layout col=lane&15, row=(lane>>4)*4+reg
#pragma unroll
  for (int j = 0; j < 4; j++) {
    const int gc = n0 + wc * 64 + j * 16 + l15;
    const float bval = bias[gc];
#pragma unroll
    for (int i = 0; i < 4; i++) {
      const int grb = m0 + wr * 64 + i * 16 + lhi * 4;
#pragma unroll
      for (int r = 0; r < 4; r++) {
        const float v = acc[i][j][r] + bval;
        const int gr = grb + r;
        if constexpr (MODE == 0) {
          ((float*)outp)[(size_t)gr * CDIM + gc] = v;
        } else {
          const int bidx = gr >> 11, n = gr & (NTOK - 1);
          const int hh = gc >> 6, dd = gc & 63;
          ((h16*)outp)[(((size_t)(bidx * NHEAD + hh)) * NTOK + n) * HDIM + dd] = (h16)v;
        }
      }
    }
  }
}

// ---------------------------------------------------------------------------
// Flash attention with trinity mask. 2-phase pipeline, KVBLK=64.
// Defer-max (THR=8 in log2 units) + deferred denominator: the per-tile shfl
// reductions are skipped unless some lane's local max exceeds m+8; the row
// sum is accumulated per-lane and reduced ONCE at the end.
__global__ __launch_bounds__(256)
void attn_kernel(const h16* __restrict__ Qh, const h16* __restrict__ Kh,
                 const h16* __restrict__ VTh, h16* __restrict__ AX) {
  __shared__ __attribute__((aligned(16))) h16 Kb[2][64 * 64];
  __shared__ __attribute__((aligned(16))) h16 Vb[2][64 * 64];
  __shared__ __attribute__((aligned(16))) h16 Pl[4][16 * 64];  // XOR-swizzled

  const int tid = threadIdx.x;
  const int lane = tid & 63;
  const int w = tid >> 6;
  const int l15 = lane & 15, lhi = lane >> 4;

  const int id = blockIdx.x;
  const int pos = id >> 3;
  const int bh = (id & 7) * 8 + (pos >> 5);   // XCD-grouped bh
  const int qblk = 31 - (pos & 31);           // text-first (long blocks early)
  const int b = bh >> 4, h = bh & 15;
  const int q0 = qblk * 64;

  const h16* qbase = Qh + (size_t)bh * NTOK * HDIM;
  const h16* kbase = Kh + (size_t)bh * NTOK * HDIM;
  const h16* vbase = VTh + (size_t)bh * HDIM * NTOK;

  // Q fragments (A operand): row = lane&15, k = (lane>>4)*8..+8
  const int qrow = q0 + w * 16 + l15;
  const f16x8 qf0 = *(const f16x8*)(qbase + (size_t)qrow * HDIM + lhi * 8);
  const f16x8 qf1 = *(const f16x8*)(qbase + (size_t)qrow * HDIM + 32 + lhi * 8);

  const bool is_img = (q0 < IMGTOK);
  int kstart, kend;
  if (is_img) { kstart = q0 & ~511; kend = kstart + 512; }
  else        { kstart = 0;         kend = q0 + 64; }
  const int nt = (kend - kstart) >> 6;

  float m_r[4], lp[4];
  f32x4 o[4] = {};
#pragma unroll
  for (int r = 0; r < 4; r++) { m_r[r] = -3.0e38f; lp[r] = 0.f; }

  // staging: physical chunk p -> row p>>3; logical col-chunk = (p&7)^(row&7)
  const int srow = tid >> 3;
  const int scc = (tid & 7) ^ (srow & 7);
#define ASTAGE(bufi, k0s)                                                     \
  do {                                                                        \
    gload_lds16(kbase + (size_t)((k0s) + srow) * HDIM + scc * 8,              \
                Kb[bufi] + tid * 8);                                          \
    gload_lds16(kbase + (size_t)((k0s) + 32 + srow) * HDIM + scc * 8,         \
                Kb[bufi] + (256 + tid) * 8);                                  \
    gload_lds16(vbase + (size_t)srow * NTOK + (k0s) + scc * 8,                \
                Vb[bufi] + tid * 8);                                          \
    gload_lds16(vbase + (size_t)(32 + srow) * NTOK + (k0s) + scc * 8,         \
                Vb[bufi] + (256 + tid) * 8);                                  \
  } while (0)

  h16* pl = &Pl[w][0];
  const float sc = 0.125f * 1.44269504088896f;  // scale * log2(e)
  const int x0 = (lhi ^ (l15 & 7)) * 8;          // swizzled chunk offsets
  const int x1 = ((lhi + 4) ^ (l15 & 7)) * 8;

  ASTAGE(0, kstart);
  asm volatile("s_waitcnt vmcnt(0)" ::: "memory");
  __builtin_amdgcn_s_barrier();
  int cur = 0;

  for (int t = 0; t < nt; ++t) {
    const int k0 = kstart + t * 64;
    if (t + 1 < nt) ASTAGE(cur ^ 1, kstart + (t + 1) * 64);

    // ---- S = Q K^T : 4 halves of 16 keys, f32 -------------------------
    const h16* Kc = Kb[cur];
    f32x4 s[4];
    __builtin_amdgcn_s_setprio(1);
#pragma unroll
    for (int hk = 0; hk < 4; ++hk) {
      const h16* kr = Kc + (hk * 16 + l15) * 64;
      const f16x8 kfa = *(const f16x8*)(kr + x0);
      const f16x8 kfb = *(const f16x8*)(kr + x1);
      f32x4 acc = {};
      acc = __builtin_amdgcn_mfma_f32_16x16x32_f16(qf0, kfa, acc, 0, 0, 0);
      acc = __builtin_amdgcn_mfma_f32_16x16x32_f16(qf1, kfb, acc, 0, 0, 0);
      s[hk] = acc;
    }
    __builtin_amdgcn_s_setprio(0);

    // ---- online softmax (defer-max, deferred sum) ---------------------
    const bool need_mask = (!is_img) && (k0 + 63 >= IMGTOK);
    float sv[4][4], lmax[4];
    bool hit = false;
#pragma unroll
    for (int r = 0; r < 4; ++r) {
#pragma unroll
      for (int hk = 0; hk < 4; ++hk) sv[r][hk] = s[hk][r] * sc;
      if (need_mask) {
        const int qg = q0 + w * 16 + lhi * 4 + r;
#pragma unroll
        for (int hk = 0; hk < 4; ++hk) {
          const int kg = k0 + hk * 16 + l15;
          if (kg >= IMGTOK && kg > qg) sv[r][hk] = -1e30f;
        }
      }
      lmax[r] = fmaxf(fmaxf(sv[r][0], sv[r][1]), fmaxf(sv[r][2], sv[r][3]));
      hit |= (lmax[r] > m_r[r] + 8.0f);
    }
    if (__any(hit)) {  // rare: full max-reduce + rescale
#pragma unroll
      for (int r = 0; r < 4; ++r) {
        float vmax = lmax[r];
        vmax = fmaxf(vmax, __shfl_xor(vmax, 1));
        vmax = fmaxf(vmax, __shfl_xor(vmax, 2));
        vmax = fmaxf(vmax, __shfl_xor(vmax, 4));
        vmax = fmaxf(vmax, __shfl_xor(vmax, 8));
        const float mnew = fmaxf(m_r[r], vmax);
        const float corr = exp2f(m_r[r] - mnew);
        m_r[r] = mnew;
        lp[r] *= corr;
#pragma unroll
        for (int dt = 0; dt < 4; dt++) o[dt][r] *= corr;
      }
    }
#pragma unroll
    for (int r = 0; r < 4; ++r) {
      const int prow = lhi * 4 + r;
      h16* pr = pl + prow * 64;
      float rs = 0.f;
#pragma unroll
      for (int hk = 0; hk < 4; ++hk) {
        const float p = exp2f(sv[r][hk] - m_r[r]);
        rs += p;
        const int c = hk * 16 + l15;
        pr[((c >> 3) ^ (prow & 7)) * 8 + (c & 7)] = (h16)p;
      }
      lp[r] += rs;
    }
    // wave-private LDS write->read ordering
    asm volatile("s_waitcnt lgkmcnt(0)" ::: "memory");
    __builtin_amdgcn_sched_barrier(0);

    // ---- PV: A = P[16q x 64k], B = V[64k x 16d] ----------------------
    const h16* Vc = Vb[cur];
    const f16x8 pf0 = *(const f16x8*)(pl + l15 * 64 + x0);
    const f16x8 pf1 = *(const f16x8*)(pl + l15 * 64 + x1);
    __builtin_amdgcn_s_setprio(1);
#pragma unroll
    for (int dt = 0; dt < 4; dt++) {
      const h16* vr = Vc + (dt * 16 + l15) * 64;
      const f16x8 vfa = *(const f16x8*)(vr + x0);
      const f16x8 vfb = *(const f16x8*)(vr + x1);
      o[dt] = __builtin_amdgcn_mfma_f32_16x16x32_f16(pf0, vfa, o[dt], 0, 0, 0);
      o[dt] = __builtin_amdgcn_mfma_f32_16x16x32_f16(pf1, vfb, o[dt], 0, 0, 0);
    }
    __builtin_amdgcn_s_setprio(0);

    asm volatile("s_waitcnt vmcnt(0)" ::: "memory");  // next tile DMA landed
    __builtin_amdgcn_s_barrier();                     // all waves off buf[cur]
    cur ^= 1;
  }
#undef ASTAGE

  // epilogue: reduce deferred denominator across the 16 key-lanes, write out
  const int qg0 = q0 + w * 16 + lhi * 4;
#pragma unroll
  for (int r = 0; r < 4; r++) {
    float l = lp[r];
    l += __shfl_xor(l, 1);
    l += __shfl_xor(l, 2);
    l += __shfl_xor(l, 4);
    l += __shfl_xor(l, 8);
    const float inv = 1.0f / l;
    const size_t row = (size_t)(b * NTOK + qg0 + r);
#pragma unroll
    for (int dt = 0; dt < 4; dt++) {
      const int col = h * 64 + dt * 16 + l15;
      AX[row * CDIM + col] = (h16)(o[dt][r] * inv);
    }
  }
}

// ---------------------------------------------------------------------------
extern "C" void kernel_launch(void* const* d_in, const int* in_sizes, int n_in,
                              void* d_out, int out_size, void* d_ws, size_t ws_size,
                              hipStream_t stream) {
  (void)in_sizes; (void)n_in; (void)out_size; (void)ws_size;
  const float* q  = (const float*)d_in[0];
  const float* kv = (const float*)d_in[1];
  const float* Wq = (const float*)d_in[2];
  const float* bq = (const float*)d_in[3];
  const float* Wk = (const float*)d_in[4];
  const float* bk = (const float*)d_in[5];
  const float* Wv = (const float*)d_in[6];
  const float* bv = (const float*)d_in[7];
  const float* Wo = (const float*)d_in[8];
  const float* bo = (const float*)d_in[9];
  float* out = (float*)d_out;

  char* ws = (char*)d_ws;
  const size_t SZ_MK = (size_t)MROWS * CDIM * sizeof(h16);  // 16 MB
  const size_t SZ_W  = (size_t)CDIM * CDIM * sizeof(h16);   // 2 MB
  h16* qb  = (h16*)(ws);
  h16* kvb = (h16*)(ws + SZ_MK);
  h16* wqt = (h16*)(ws + 2 * SZ_MK);
  h16* wkt = (h16*)(ws + 2 * SZ_MK + SZ_W);
  h16* wvt = (h16*)(ws + 2 * SZ_MK + 2 * SZ_W);
  h16* wot = (h16*)(ws + 2 * SZ_MK + 3 * SZ_W);
  h16* Qh  = (h16*)(ws + 2 * SZ_MK + 4 * SZ_W);
  h16* Kh  = (h16*)(ws + 3 * SZ_MK + 4 * SZ_W);
  h16* VTh = (h16*)(ws + 4 * SZ_MK + 4 * SZ_W);
  h16* ax  = (h16*)(ws);  // overlays qb (qb dead after Q projection)

  cvt_f16<<<4096, 256, 0, stream>>>(q, qb);
  cvt_f16<<<4096, 256, 0, stream>>>(kv, kvb);
  wtrans<<<dim3(32, 32, 4), dim3(32, 8), 0, stream>>>(Wq, Wk, Wv, Wo,
                                                      wqt, wkt, wvt, wot);
  gemm_bt<1><<<dim3(8, 64), 256, 0, stream>>>(qb, wqt, bq, (void*)Qh);
  gemm_bt<1><<<dim3(8, 64), 256, 0, stream>>>(kvb, wkt, bk, (void*)Kh);
  gemm_bt<2><<<dim3(8, 64), 256, 0, stream>>>(kvb, wvt, bv, (void*)VTh);
  attn_kernel<<<2048, 256, 0, stream>>>(Qh, Kh, VTh, ax);
  gemm_bt<0><<<dim3(8, 64), 256, 0, stream>>>(ax, wot, bo, (void*)out);
}

// Round 5
// 329.079 us; speedup vs baseline: 1.7602x; 1.0319x over previous
//
#include <hip/hip_runtime.h>

// ---------------------------------------------------------------------------
// CrossAttention (trinity mask) on MI355X.
// B=4, N=2048 (IMG=1536 in 3 chunks of 512, TXT=512), C=1024, H=16, d=64.
// R4b: compile fix (cvt_pkrtz returns __fp16-vector, bit_cast it).
//     attn uses swapped QK^T (lane owns a q-row -> lane-local softmax,
//     P store = cvt_pkrtz pairs + 4 ds_write_b64); softmax scale folded into
//     the Q projection; GEMM moves to 3-buffer 48KB counted-vmcnt pipeline
//     (3 blocks/CU instead of 2).
// fp16 fragments + f32 accumulation (bf16 would blow absmax through the
// 4-matmul chain; fp16 is same MFMA rate on gfx950).
// ---------------------------------------------------------------------------

typedef _Float16 h16;
typedef _Float16 f16x8 __attribute__((ext_vector_type(8)));
typedef __fp16 fp16v2 __attribute__((ext_vector_type(2)));
typedef float f32x4 __attribute__((ext_vector_type(4)));

#define BATCH 4
#define NTOK  2048
#define CDIM  1024
#define NHEAD 16
#define HDIM  64
#define IMGTOK 1536
#define MROWS (BATCH * NTOK)   // 8192
#define QSCALE 0.18033688011112042f   /* 0.125 * log2(e) */

__device__ __forceinline__ void gload_lds16(const void* g, void* l) {
  __builtin_amdgcn_global_load_lds(
      (const __attribute__((address_space(1))) unsigned int*)g,
      (__attribute__((address_space(3))) unsigned int*)l, 16, 0, 0);
}

// ---------------------------------------------------------------------------
// f32 -> fp16 elementwise convert, 8 elems/thread
__global__ __launch_bounds__(256)
void cvt_f16(const float* __restrict__ s, h16* __restrict__ d) {
  size_t i = ((size_t)blockIdx.x * 256 + threadIdx.x) * 8;
  float4 a = *(const float4*)(s + i);
  float4 b = *(const float4*)(s + i + 4);
  f16x8 o;
  o[0] = (h16)a.x; o[1] = (h16)a.y; o[2] = (h16)a.z; o[3] = (h16)a.w;
  o[4] = (h16)b.x; o[5] = (h16)b.y; o[6] = (h16)b.z; o[7] = (h16)b.w;
  *(f16x8*)(d + i) = o;
}

// ---------------------------------------------------------------------------
// W [K=1024][N=1024] f32  ->  WT [N][K] fp16   (4 weights via blockIdx.z)
__global__ __launch_bounds__(256)
void wtrans(const float* __restrict__ W0, const float* __restrict__ W1,
            const float* __restrict__ W2, const float* __restrict__ W3,
            h16* __restrict__ T0, h16* __restrict__ T1,
            h16* __restrict__ T2, h16* __restrict__ T3) {
  const float* W; h16* T;
  switch (blockIdx.z) {
    case 0: W = W0; T = T0; break;
    case 1: W = W1; T = T1; break;
    case 2: W = W2; T = T2; break;
    default: W = W3; T = T3; break;
  }
  __shared__ float t[32][33];
  const int n0 = blockIdx.x * 32, k0 = blockIdx.y * 32;
  const int tx = threadIdx.x, ty = threadIdx.y;  // (32,8)
#pragma unroll
  for (int i = 0; i < 4; i++)
    t[ty + 8 * i][tx] = W[(size_t)(k0 + ty + 8 * i) * CDIM + n0 + tx];
  __syncthreads();
#pragma unroll
  for (int i = 0; i < 4; i++)
    T[(size_t)(n0 + ty + 8 * i) * CDIM + k0 + tx] = (h16)t[tx][ty + 8 * i];
}

// ---------------------------------------------------------------------------
// GEMM: C[M=8192][1024] = X[8192][1024] @ WT^T + bias
// WT is [N][K] row-major. 128x128 tile, BK=32, 4 waves.
// 3-buffer pipeline (48KB -> 3 blocks/CU), counted vmcnt(4), depth-2 cover,
// one barrier per iteration. LDS chunk-XOR swizzle for conflict-light reads.
// MODE 0: f32 out row-major (+bias)
// MODE 1: fp16 out heads layout   [B,H,N,64]
// MODE 2: fp16 out heads-T layout [B,H,64,N] via LDS-transpose epilogue
// MODE 3: like MODE 1 but scaled by QSCALE (for Q projection)
template <int MODE>
__global__ __launch_bounds__(256, 3)
void gemm_bt(const h16* __restrict__ X, const h16* __restrict__ WT,
             const float* __restrict__ bias, void* __restrict__ outp) {
  // 3 bufs x (A 4096 + B 4096) h16 = 48 KiB
  __shared__ __attribute__((aligned(16))) h16 smem[3 * 8192];
  const int tid = threadIdx.x;
  const int lane = tid & 63;
  const int w = tid >> 6;
  const int wr = w >> 1, wc = w & 1;
  const int l15 = lane & 15, lhi = lane >> 4;
  const int m0 = blockIdx.y * 128;
  const int n0 = blockIdx.x * 128;

  f32x4 acc[4][4] = {};

  const int sr = tid >> 2;                    // staging row 0..63 (and +64)
  const int pc = tid & 3;                     // physical chunk
  const int lc = pc ^ ((sr >> 1) & 3);        // logical chunk (same for sr+64)
  const h16* gA0 = X + (size_t)(m0 + sr) * CDIM + lc * 8;
  const h16* gA1 = gA0 + (size_t)64 * CDIM;
  const h16* gB0 = WT + (size_t)(n0 + sr) * CDIM + lc * 8;
  const h16* gB1 = gB0 + (size_t)64 * CDIM;

#define GSTAGE(bi, kt)                                      \
  do {                                                      \
    h16* A_ = smem + (bi) * 8192;                           \
    h16* B_ = A_ + 4096;                                    \
    gload_lds16(gA0 + (kt) * 32, A_ + tid * 8);             \
    gload_lds16(gA1 + (kt) * 32, A_ + (256 + tid) * 8);     \
    gload_lds16(gB0 + (kt) * 32, B_ + tid * 8);             \
    gload_lds16(gB1 + (kt) * 32, B_ + (256 + tid) * 8);     \
  } while (0)

  const int NT = CDIM / 32;  // 32
  GSTAGE(0, 0);
  GSTAGE(1, 1);
  const int rswz = (l15 >> 1) & 3;   // frag-read chunk swizzle (row-derived)

  int rb = 0, sb = 2;
  for (int kt = 0; kt < NT; ++kt) {
    if (kt + 1 < NT) asm volatile("s_waitcnt vmcnt(4)" ::: "memory");
    else             asm volatile("s_waitcnt vmcnt(0)" ::: "memory");
    __builtin_amdgcn_s_barrier();
    if (kt + 2 < NT) { GSTAGE(sb, kt + 2); sb = (sb == 2) ? 0 : sb + 1; }
    const h16* A_ = smem + rb * 8192;
    const h16* B_ = A_ + 4096;
    rb = (rb == 2) ? 0 : rb + 1;
    f16x8 a[4], bb[4];
#pragma unroll
    for (int i = 0; i < 4; i++)
      a[i] = *(const f16x8*)(A_ + (wr * 64 + i * 16 + l15) * 32 + (lhi ^ rswz) * 8);
#pragma unroll
    for (int i = 0; i < 4; i++)
      bb[i] = *(const f16x8*)(B_ + (wc * 64 + i * 16 + l15) * 32 + (lhi ^ rswz) * 8);
    __builtin_amdgcn_s_setprio(1);
#pragma unroll
    for (int i = 0; i < 4; i++)
#pragma unroll
      for (int j = 0; j < 4; j++)
        acc[i][j] = __builtin_amdgcn_mfma_f32_16x16x32_f16(a[i], bb[j], acc[i][j], 0, 0, 0);
    __builtin_amdgcn_s_setprio(0);
  }
#undef GSTAGE

  if constexpr (MODE == 2) {
    // LDS-transpose epilogue: T[gcL][grL], chunk-swizzled, then coalesced
    // 256B-row stores into [B,H,64,N].
    __builtin_amdgcn_s_barrier();
    h16* T = smem;  // [128][128] h16, chunk = (grL>>3) ^ (gcL&15)
#pragma unroll
    for (int j = 0; j < 4; j++) {
      const int gcL = wc * 64 + j * 16 + l15;
      const float bval = bias[n0 + gcL];
#pragma unroll
      for (int i = 0; i < 4; i++) {
#pragma unroll
        for (int r = 0; r < 4; r++) {
          const int grL = wr * 64 + i * 16 + lhi * 4 + r;
          const int ch = (grL >> 3) ^ (gcL & 15);
          T[gcL * 128 + ch * 8 + (grL & 7)] = (h16)(acc[i][j][r] + bval);
        }
      }
    }
    __builtin_amdgcn_s_barrier();
    const int bsel = m0 >> 11;
    const int nbase = m0 & (NTOK - 1);
    h16* outh = (h16*)outp;
#pragma unroll
    for (int pass = 0; pass < 8; ++pass) {
      const int rowL = pass * 16 + (tid >> 4);   // 0..127 (output row = gc)
      const int c = tid & 15;                    // chunk of 8 grL
      const int gc = n0 + rowL;
      const int hh = gc >> 6, dd = gc & 63;
      f16x8 v = *(const f16x8*)(T + rowL * 128 + ((c ^ (rowL & 15)) * 8));
      *(f16x8*)(outh + (((size_t)(bsel * NHEAD + hh)) * HDIM + dd) * NTOK +
                nbase + c * 8) = v;
    }
    return;
  }

  // MODE 0/1/3 epilogue: D layout col=lane&15, row=(lane>>4)*4+reg
#pragma unroll
  for (int j = 0; j < 4; j++) {
    const int gc = n0 + wc * 64 + j * 16 + l15;
    const float bval = bias[gc];
#pragma unroll
    for (int i = 0; i < 4; i++) {
      const int grb = m0 + wr * 64 + i * 16 + lhi * 4;
#pragma unroll
      for (int r = 0; r < 4; r++) {
        float v = acc[i][j][r] + bval;
        if constexpr (MODE == 3) v *= QSCALE;
        const int gr = grb + r;
        if constexpr (MODE == 0) {
          ((float*)outp)[(size_t)gr * CDIM + gc] = v;
        } else {
          const int bidx = gr >> 11, n = gr & (NTOK - 1);
          const int hh = gc >> 6, dd = gc & 63;
          ((h16*)outp)[(((size_t)(bidx * NHEAD + hh)) * NTOK + n) * HDIM + dd] = (h16)v;
        }
      }
    }
  }
}

// ---------------------------------------------------------------------------
// Flash attention with trinity mask. 2-phase pipeline, KVBLK=64.
// Swapped QK^T: D[16k x 16q], col=lane&15=q -> each lane owns one q-row.
// Row max/sum are lane-local partials (reduce over lhi groups only on the
// rare defer-max hit). P stored via cvt_pkrtz pairs + 4 ds_write_b64 into
// the PV-friendly [q][k] layout (16B-granule XOR swizzle, read side as R3).
// Q projection is pre-scaled by 0.125*log2(e), so scores feed exp2 directly.
__global__ __launch_bounds__(256)
void attn_kernel(const h16* __restrict__ Qh, const h16* __restrict__ Kh,
                 const h16* __restrict__ VTh, h16* __restrict__ AX) {
  __shared__ __attribute__((aligned(16))) h16 Kb[2][64 * 64];
  __shared__ __attribute__((aligned(16))) h16 Vb[2][64 * 64];
  __shared__ __attribute__((aligned(16))) h16 Pl[4][16 * 64];  // XOR-swizzled

  const int tid = threadIdx.x;
  const int lane = tid & 63;
  const int w = tid >> 6;
  const int l15 = lane & 15, lhi = lane >> 4;
  const int lhi4 = lhi * 4;

  const int id = blockIdx.x;
  const int pos = id >> 3;
  const int bh = (id & 7) * 8 + (pos >> 5);   // XCD-grouped bh
  const int qblk = 31 - (pos & 31);           // text-first (long blocks early)
  const int b = bh >> 4, h = bh & 15;
  const int q0 = qblk * 64;

  const h16* qbase = Qh + (size_t)bh * NTOK * HDIM;
  const h16* kbase = Kh + (size_t)bh * NTOK * HDIM;
  const h16* vbase = VTh + (size_t)bh * HDIM * NTOK;

  // Q fragments (B operand after swap): col=lane&15 -> q-row, k=(lane>>4)*8
  const int qrow = q0 + w * 16 + l15;
  const f16x8 qf0 = *(const f16x8*)(qbase + (size_t)qrow * HDIM + lhi * 8);
  const f16x8 qf1 = *(const f16x8*)(qbase + (size_t)qrow * HDIM + 32 + lhi * 8);
  const int qg = qrow;  // this lane's global q index (for masking)

  const bool is_img = (q0 < IMGTOK);
  int kstart, kend;
  if (is_img) { kstart = q0 & ~511; kend = kstart + 512; }
  else        { kstart = 0;         kend = q0 + 64; }
  const int nt = (kend - kstart) >> 6;

  float m = -3.0e38f, lp = 0.f;
  f32x4 o[4] = {};

  // staging: physical chunk p -> row p>>3; logical col-chunk = (p&7)^(row&7)
  const int srow = tid >> 3;
  const int scc = (tid & 7) ^ (srow & 7);
#define ASTAGE(bufi, k0s)                                                     \
  do {                                                                        \
    gload_lds16(kbase + (size_t)((k0s) + srow) * HDIM + scc * 8,              \
                Kb[bufi] + tid * 8);                                          \
    gload_lds16(kbase + (size_t)((k0s) + 32 + srow) * HDIM + scc * 8,         \
                Kb[bufi] + (256 + tid) * 8);                                  \
    gload_lds16(vbase + (size_t)srow * NTOK + (k0s) + scc * 8,                \
                Vb[bufi] + tid * 8);                                          \
    gload_lds16(vbase + (size_t)(32 + srow) * NTOK + (k0s) + scc * 8,         \
                Vb[bufi] + (256 + tid) * 8);                                  \
  } while (0)

  h16* pl = &Pl[w][0];
  const int x0 = (lhi ^ (l15 & 7)) * 8;          // swizzled chunk offsets
  const int x1 = ((lhi + 4) ^ (l15 & 7)) * 8;
  // P-write: quad (hk) at k = hk*16 + lhi*4, row = l15
  const int pswz = l15 & 7;
  const int phalf = (lhi & 1) * 4;
  const int plhi2 = lhi >> 1;
  h16* prb = pl + l15 * 64;

  ASTAGE(0, kstart);
  asm volatile("s_waitcnt vmcnt(0)" ::: "memory");
  __builtin_amdgcn_s_barrier();
  int cur = 0;

  for (int t = 0; t < nt; ++t) {
    const int k0 = kstart + t * 64;
    if (t + 1 < nt) ASTAGE(cur ^ 1, kstart + (t + 1) * 64);

    // ---- S^T = K Q^T : 4 blocks of 16 keys ---------------------------
    const h16* Kc = Kb[cur];
    f32x4 s[4];
    __builtin_amdgcn_s_setprio(1);
#pragma unroll
    for (int hk = 0; hk < 4; ++hk) {
      const h16* kr = Kc + (hk * 16 + l15) * 64;
      const f16x8 kfa = *(const f16x8*)(kr + x0);
      const f16x8 kfb = *(const f16x8*)(kr + x1);
      f32x4 acc = {};
      acc = __builtin_amdgcn_mfma_f32_16x16x32_f16(kfa, qf0, acc, 0, 0, 0);
      acc = __builtin_amdgcn_mfma_f32_16x16x32_f16(kfb, qf1, acc, 0, 0, 0);
      s[hk] = acc;
    }
    __builtin_amdgcn_s_setprio(0);

    // ---- lane-local softmax (defer-max, deferred sum) -----------------
    const bool need_mask = (!is_img) && (k0 + 63 >= IMGTOK);
    float sv[4][4];
    float lmax = -3.0e38f;
#pragma unroll
    for (int hk = 0; hk < 4; ++hk) {
#pragma unroll
      for (int r = 0; r < 4; ++r) {
        float v = s[hk][r];
        if (need_mask) {
          const int kg = k0 + hk * 16 + lhi4 + r;
          if (kg >= IMGTOK && kg > qg) v = -1e30f;
        }
        sv[hk][r] = v;
        lmax = fmaxf(lmax, v);
      }
    }
    if (__any(lmax > m + 8.0f)) {   // rare: row-reduce + rescale
      float vmax = fmaxf(lmax, __shfl_xor(lmax, 16));
      vmax = fmaxf(vmax, __shfl_xor(vmax, 32));
      const float mnew = fmaxf(m, vmax);
      const float corr = exp2f(m - mnew);
      m = mnew;
      lp *= corr;
      const float c0 = __shfl(corr, lhi4 + 0);
      const float c1 = __shfl(corr, lhi4 + 1);
      const float c2 = __shfl(corr, lhi4 + 2);
      const float c3 = __shfl(corr, lhi4 + 3);
#pragma unroll
      for (int dt = 0; dt < 4; dt++) {
        o[dt][0] *= c0; o[dt][1] *= c1; o[dt][2] *= c2; o[dt][3] *= c3;
      }
    }
#pragma unroll
    for (int hk = 0; hk < 4; ++hk) {
      const float e0 = exp2f(sv[hk][0] - m);
      const float e1 = exp2f(sv[hk][1] - m);
      const float e2 = exp2f(sv[hk][2] - m);
      const float e3 = exp2f(sv[hk][3] - m);
      lp += (e0 + e1) + (e2 + e3);
      const fp16v2 lo2 = __builtin_amdgcn_cvt_pkrtz(e0, e1);
      const fp16v2 hi2 = __builtin_amdgcn_cvt_pkrtz(e2, e3);
      uint2 qw;
      qw.x = __builtin_bit_cast(unsigned int, lo2);
      qw.y = __builtin_bit_cast(unsigned int, hi2);
      *(uint2*)(prb + ((hk * 2 + plhi2) ^ pswz) * 8 + phalf) = qw;
    }
    // wave-private LDS write->read ordering
    asm volatile("s_waitcnt lgkmcnt(0)" ::: "memory");
    __builtin_amdgcn_sched_barrier(0);

    // ---- PV: A = P[16q x 64k], B = V[64k x 16d] ----------------------
    const h16* Vc = Vb[cur];
    const f16x8 pf0 = *(const f16x8*)(pl + l15 * 64 + x0);
    const f16x8 pf1 = *(const f16x8*)(pl + l15 * 64 + x1);
    __builtin_amdgcn_s_setprio(1);
#pragma unroll
    for (int dt = 0; dt < 4; dt++) {
      const h16* vr = Vc + (dt * 16 + l15) * 64;
      const f16x8 vfa = *(const f16x8*)(vr + x0);
      const f16x8 vfb = *(const f16x8*)(vr + x1);
      o[dt] = __builtin_amdgcn_mfma_f32_16x16x32_f16(pf0, vfa, o[dt], 0, 0, 0);
      o[dt] = __builtin_amdgcn_mfma_f32_16x16x32_f16(pf1, vfb, o[dt], 0, 0, 0);
    }
    __builtin_amdgcn_s_setprio(0);

    asm volatile("s_waitcnt vmcnt(0)" ::: "memory");  // next tile DMA landed
    __builtin_amdgcn_s_barrier();                     // all waves off buf[cur]
    cur ^= 1;
  }
#undef ASTAGE

  // epilogue: finish denominator (reduce over lhi groups), write out
  float l = lp;
  l += __shfl_xor(l, 16);
  l += __shfl_xor(l, 32);
  const int qg0 = q0 + w * 16 + lhi4;
#pragma unroll
  for (int r = 0; r < 4; r++) {
    const float lr = __shfl(l, lhi4 + r);
    const float inv = 1.0f / lr;
    const size_t row = (size_t)(b * NTOK + qg0 + r);
#pragma unroll
    for (int dt = 0; dt < 4; dt++) {
      const int col = h * 64 + dt * 16 + l15;
      AX[row * CDIM + col] = (h16)(o[dt][r] * inv);
    }
  }
}

// ---------------------------------------------------------------------------
extern "C" void kernel_launch(void* const* d_in, const int* in_sizes, int n_in,
                              void* d_out, int out_size, void* d_ws, size_t ws_size,
                              hipStream_t stream) {
  (void)in_sizes; (void)n_in; (void)out_size; (void)ws_size;
  const float* q  = (const float*)d_in[0];
  const float* kv = (const float*)d_in[1];
  const float* Wq = (const float*)d_in[2];
  const float* bq = (const float*)d_in[3];
  const float* Wk = (const float*)d_in[4];
  const float* bk = (const float*)d_in[5];
  const float* Wv = (const float*)d_in[6];
  const float* bv = (const float*)d_in[7];
  const float* Wo = (const float*)d_in[8];
  const float* bo = (const float*)d_in[9];
  float* out = (float*)d_out;

  char* ws = (char*)d_ws;
  const size_t SZ_MK = (size_t)MROWS * CDIM * sizeof(h16);  // 16 MB
  const size_t SZ_W  = (size_t)CDIM * CDIM * sizeof(h16);   // 2 MB
  h16* qb  = (h16*)(ws);
  h16* kvb = (h16*)(ws + SZ_MK);
  h16* wqt = (h16*)(ws + 2 * SZ_MK);
  h16* wkt = (h16*)(ws + 2 * SZ_MK + SZ_W);
  h16* wvt = (h16*)(ws + 2 * SZ_MK + 2 * SZ_W);
  h16* wot = (h16*)(ws + 2 * SZ_MK + 3 * SZ_W);
  h16* Qh  = (h16*)(ws + 2 * SZ_MK + 4 * SZ_W);
  h16* Kh  = (h16*)(ws + 3 * SZ_MK + 4 * SZ_W);
  h16* VTh = (h16*)(ws + 4 * SZ_MK + 4 * SZ_W);
  h16* ax  = (h16*)(ws);  // overlays qb (qb dead after Q projection)

  cvt_f16<<<4096, 256, 0, stream>>>(q, qb);
  cvt_f16<<<4096, 256, 0, stream>>>(kv, kvb);
  wtrans<<<dim3(32, 32, 4), dim3(32, 8), 0, stream>>>(Wq, Wk, Wv, Wo,
                                                      wqt, wkt, wvt, wot);
  gemm_bt<3><<<dim3(8, 64), 256, 0, stream>>>(qb, wqt, bq, (void*)Qh);
  gemm_bt<1><<<dim3(8, 64), 256, 0, stream>>>(kvb, wkt, bk, (void*)Kh);
  gemm_bt<2><<<dim3(8, 64), 256, 0, stream>>>(kvb, wvt, bv, (void*)VTh);
  attn_kernel<<<2048, 256, 0, stream>>>(Qh, Kh, VTh, ax);
  gemm_bt<0><<<dim3(8, 64), 256, 0, stream>>>(ax, wot, bo, (void*)out);
}